// Round 9
// baseline (80.981 us; speedup 1.0000x reference)
//
#include <hip/hip_runtime.h>
#include <math.h>

#define NN 8192
#define CC 256
#define OO 64
#define JW 8      // j's per wave in k_rank

// ============ K1: GEMM (W1 -> LDS transposed) + f1/f2 + exp tables + sortable keys ============
__global__ __launch_bounds__(256) void k_gemm(
    const float* __restrict__ x, const float* __restrict__ W1,
    const float* __restrict__ b1, const float* __restrict__ a1,
    const float* __restrict__ ba1, const float* __restrict__ a2,
    const float* __restrict__ ba2,
    float* __restrict__ seq,
    float* __restrict__ f1, float* __restrict__ f2,
    float* __restrict__ E1, float* __restrict__ E1s,
    float* __restrict__ eF2, float* __restrict__ eF2s,
    unsigned long long* __restrict__ keys /* [2][NN] */)
{
  __shared__ float w_lds[64][66];
  const int t = threadIdx.x;
  const int p = t & 31;             // col pair: o = 2p, 2p+1
  const int g = t >> 5;             // 0..7 row group
  const int r0 = blockIdx.x*16 + g*2;
  const int r1 = r0 + 1;
  float c00 = 0.f, c01 = 0.f, c10 = 0.f, c11 = 0.f;
  for (int ct = 0; ct < 4; ++ct) {
    __syncthreads();
    for (int idx = t; idx < 4096; idx += 256) {
      const int o = idx >> 6, cc = idx & 63;
      w_lds[cc][o] = W1[o*CC + ct*64 + cc];
    }
    __syncthreads();
    const float* xr0 = x + (size_t)r0*CC + ct*64;
    const float* xr1 = x + (size_t)r1*CC + ct*64;
#pragma unroll 4
    for (int c = 0; c < 64; c += 4) {
      const float4 xa = *(const float4*)(xr0 + c);
      const float4 xb = *(const float4*)(xr1 + c);
      const float2 w0 = *(const float2*)&w_lds[c+0][2*p];
      const float2 w1 = *(const float2*)&w_lds[c+1][2*p];
      const float2 w2 = *(const float2*)&w_lds[c+2][2*p];
      const float2 w3 = *(const float2*)&w_lds[c+3][2*p];
      c00 = fmaf(xa.x, w0.x, c00); c00 = fmaf(xa.y, w1.x, c00);
      c00 = fmaf(xa.z, w2.x, c00); c00 = fmaf(xa.w, w3.x, c00);
      c01 = fmaf(xa.x, w0.y, c01); c01 = fmaf(xa.y, w1.y, c01);
      c01 = fmaf(xa.z, w2.y, c01); c01 = fmaf(xa.w, w3.y, c01);
      c10 = fmaf(xb.x, w0.x, c10); c10 = fmaf(xb.y, w1.x, c10);
      c10 = fmaf(xb.z, w2.x, c10); c10 = fmaf(xb.w, w3.x, c10);
      c11 = fmaf(xb.x, w0.y, c11); c11 = fmaf(xb.y, w1.y, c11);
      c11 = fmaf(xb.z, w2.y, c11); c11 = fmaf(xb.w, w3.y, c11);
    }
  }
  const float2 B2 = *(const float2*)&b1[2*p];
  const float v00 = c00 + B2.x, v01 = c01 + B2.y;
  const float v10 = c10 + B2.x, v11 = c11 + B2.y;
  *(float2*)&seq[(size_t)r0*OO + 2*p] = make_float2(v00, v01);
  *(float2*)&seq[(size_t)r1*OO + 2*p] = make_float2(v10, v11);
  const float2 A1 = *(const float2*)&a1[2*p];
  const float2 A2 = *(const float2*)&a2[2*p];
  float p1_0 = v00*A1.x + v01*A1.y;
  float p2_0 = v00*A2.x + v01*A2.y;
  float p1_1 = v10*A1.x + v11*A1.y;
  float p2_1 = v10*A2.x + v11*A2.y;
#pragma unroll
  for (int d = 1; d < 32; d <<= 1) {
    p1_0 += __shfl_xor(p1_0, d, 64);
    p2_0 += __shfl_xor(p2_0, d, 64);
    p1_1 += __shfl_xor(p1_1, d, 64);
    p2_1 += __shfl_xor(p2_1, d, 64);
  }
  if (p == 0) {
    const float bba1 = ba1[0], bba2 = ba2[0];
    const float t1a = p1_0 + bba1, t2a = p2_0 + bba2;
    const float t1b = p1_1 + bba1, t2b = p2_1 + bba2;
    f1[r0] = t1a; E1[r0] = expf(t1a); E1s[r0] = expf(0.01f*t1a);
    f2[r0] = t2a; eF2[r0] = expf(t2a); eF2s[r0] = expf(0.01f*t2a);
    f1[r1] = t1b; E1[r1] = expf(t1b); E1s[r1] = expf(0.01f*t1b);
    f2[r1] = t2b; eF2[r1] = expf(t2b); eF2s[r1] = expf(0.01f*t2b);
    unsigned u;
    u = __float_as_uint(t1a); u = (u & 0x80000000u) ? ~u : (u | 0x80000000u);
    keys[r0] = ((unsigned long long)u << 32) | (unsigned)r0;
    u = __float_as_uint(t1b); u = (u & 0x80000000u) ? ~u : (u | 0x80000000u);
    keys[r1] = ((unsigned long long)u << 32) | (unsigned)r1;
    u = __float_as_uint(t2a); u = (u & 0x80000000u) ? ~u : (u | 0x80000000u);
    keys[NN + r0] = ((unsigned long long)u << 32) | (unsigned)r0;
    u = __float_as_uint(t2b); u = (u & 0x80000000u) ? ~u : (u | 0x80000000u);
    keys[NN + r1] = ((unsigned long long)u << 32) | (unsigned)r1;
  }
}

// ============ K2: rank counting + sorted scatters (f1 side: +inv1; f2 side: +sorted exp tables) ============
__global__ __launch_bounds__(512) void k_rank(
    const unsigned long long* __restrict__ keys,
    const float* __restrict__ f1, const float* __restrict__ E1,
    const float* __restrict__ E1s, const float* __restrict__ f2,
    const float* __restrict__ eF2, const float* __restrict__ eF2s,
    float* __restrict__ s1, float* __restrict__ se1, float* __restrict__ se1s,
    int* __restrict__ inv1,
    float* __restrict__ f2s, float* __restrict__ eF2srt,
    float* __restrict__ eF2ssrt, int* __restrict__ inv)
{
  const int t = threadIdx.x;
  const int lane = t & 63, wv = t >> 6;        // 8 waves
  const int gw = blockIdx.x*8 + wv;            // 0..2047
  const int bj = gw*JW;
  const int arr = bj >> 13;                    // uniform per block
  const int jb = bj & (NN-1);
  const unsigned long long* kb = keys + ((size_t)arr << 13);
  unsigned long long K[JW];
#pragma unroll
  for (int q = 0; q < JW; ++q) {
    const unsigned long long kk = kb[jb + q];
    const unsigned lo = __builtin_amdgcn_readfirstlane((unsigned)kk);
    const unsigned hi = __builtin_amdgcn_readfirstlane((unsigned)(kk >> 32));
    K[q] = ((unsigned long long)hi << 32) | lo;
  }
  int cnt[JW];
#pragma unroll
  for (int q = 0; q < JW; ++q) cnt[q] = 0;
#pragma unroll 4
  for (int c = 0; c < NN/64; ++c) {
    const unsigned long long sk = kb[c*64 + lane];
#pragma unroll
    for (int q = 0; q < JW; ++q)
      cnt[q] += (sk < K[q]) ? 1 : 0;
  }
#pragma unroll
  for (int q = 0; q < JW; ++q) {
    int r = cnt[q];
#pragma unroll
    for (int d = 1; d < 64; d <<= 1) r += __shfl_xor(r, d, 64);
    if (lane == 0) {
      const int i = jb + q;
      if (arr == 0) {
        s1[r] = f1[i]; se1[r] = E1[i]; se1s[r] = E1s[i]; inv1[r] = i;
      } else {
        inv[r] = i; f2s[r] = f2[i]; eF2srt[r] = eF2[i]; eF2ssrt[r] = eF2s[i];
      }
    }
  }
}

// ============ K3: D-factors (kk-contiguous) + kpos counts + TU/TV chunk totals ============
// grid 256 x 1024: block b owns sorted positions kk, r in [32b, 32b+32)
__global__ __launch_bounds__(1024) void k_DT(
    const float* __restrict__ se1, const float* __restrict__ se1s,
    const float* __restrict__ s1g, const float* __restrict__ f2g,
    const float* __restrict__ f2s, const float* __restrict__ eF2srt,
    const float* __restrict__ eF2ssrt, const int* __restrict__ inv,
    const float* __restrict__ seq,
    float* __restrict__ Bs, float* __restrict__ Es,
    int* __restrict__ kpos, float* __restrict__ TU, float* __restrict__ TV)
{
  __shared__ float s1l[NN];          // 32 KB
  __shared__ float csA[256], csB[256];
  __shared__ float csEA[257], csEB[257];
  __shared__ float bsl[32], esl[32];
  __shared__ float redU[16][64], redV[16][64];
  const int t = threadIdx.x;
  const int b = blockIdx.x;
  const float4 a0 = ((const float4*)se1 )[t*2];
  const float4 a1v = ((const float4*)se1 )[t*2+1];
  const float4 b0 = ((const float4*)se1s)[t*2];
  const float4 b1v = ((const float4*)se1s)[t*2+1];
  ((float4*)s1l)[t*2]   = ((const float4*)s1g)[t*2];
  ((float4*)s1l)[t*2+1] = ((const float4*)s1g)[t*2+1];
  float sa = ((a0.x+a0.y)+(a0.z+a0.w)) + ((a1v.x+a1v.y)+(a1v.z+a1v.w));
  float sb = ((b0.x+b0.y)+(b0.z+b0.w)) + ((b1v.x+b1v.y)+(b1v.z+b1v.w));
  sa += __shfl_xor(sa, 1, 64); sb += __shfl_xor(sb, 1, 64);
  sa += __shfl_xor(sa, 2, 64); sb += __shfl_xor(sb, 2, 64);
  if ((t & 3) == 0) { csA[t>>2] = sa; csB[t>>2] = sb; }   // chunk(32) sums
  __syncthreads();
  for (int d = 1; d < 256; d <<= 1) {
    float pa = 0.f, pb = 0.f;
    if (t >= d && t < 256) { pa = csA[t-d]; pb = csB[t-d]; }
    __syncthreads();
    if (t < 256) { csA[t] += pa; csB[t] += pb; }
    __syncthreads();
  }
  if (t < 256) { csEA[t+1] = csA[t]; csEB[t+1] = csB[t]; }
  if (t == 0)  { csEA[0] = 0.f; csEB[0] = 0.f; }
  __syncthreads();
  const int wv = t >> 6, lane = t & 63;
  const int half = lane >> 5, m = lane & 31;
  // --- D part: kk-contiguous, sorted inputs ---
  {
    const int kk = b*32 + 2*wv + half;
    const float tgt = -f2s[kk];
    int pos = 0;
#pragma unroll
    for (int s = NN; s; s >>= 1) {
      const int c = pos + s;
      if (c <= NN && s1l[c-1] < tgt) pos = c;
    }
    const int base = pos & ~31, cn = pos & 31;
    float ta = 0.f, tb = 0.f;
    if (m < cn) { ta = se1[base+m]; tb = se1s[base+m]; }
#pragma unroll
    for (int d = 1; d < 32; d <<= 1) {
      ta += __shfl_xor(ta, d, 64);
      tb += __shfl_xor(tb, d, 64);
    }
    if (m == 0) {
      const float PreA = csEA[pos>>5] + ta;
      const float PreB = csEB[pos>>5] + tb;
      const float T1 = csEA[256];
      const float e2 = eF2srt[kk], e2s = eF2ssrt[kk];
      const float D = fmaf(T1 - PreA, e2, PreB * e2s);
      const float bsv = e2 / D, esv = e2s / D;
      Bs[kk] = bsv; Es[kk] = esv;
      bsl[2*wv + half] = bsv; esl[2*wv + half] = esv;
    }
  }
  // --- kpos part: kpos[r] = #{ f2[j] < -s1[r] } for r in [32b, 32b+32) ---
  {
    const float tgt0 = -s1l[b*32 + 2*wv];
    const float tgt1 = -s1l[b*32 + 2*wv + 1];
    int c0 = 0, c1 = 0;
#pragma unroll 4
    for (int c = 0; c < NN/64; ++c) {
      const float fv = f2g[c*64 + lane];
      c0 += (fv < tgt0) ? 1 : 0;
      c1 += (fv < tgt1) ? 1 : 0;
    }
#pragma unroll
    for (int d = 1; d < 64; d <<= 1) {
      c0 += __shfl_xor(c0, d, 64);
      c1 += __shfl_xor(c1, d, 64);
    }
    if (lane == 0) {
      kpos[b*32 + 2*wv]     = c0;
      kpos[b*32 + 2*wv + 1] = c1;
    }
  }
  __syncthreads();
  // --- TU/TV: chunk b column totals from LDS factors ---
  {
    const int kk0 = b*32 + 2*wv, kk1 = kk0 + 1;
    const float s0v = seq[(size_t)inv[kk0]*OO + lane];
    const float s1v = seq[(size_t)inv[kk1]*OO + lane];
    redU[wv][lane] = bsl[2*wv]*s0v + bsl[2*wv+1]*s1v;
    redV[wv][lane] = esl[2*wv]*s0v + esl[2*wv+1]*s1v;
  }
  __syncthreads();
  if (wv == 0) {
    float r = 0.f;
#pragma unroll
    for (int q = 0; q < 16; ++q) r += redU[q][lane];
    TU[b*64 + lane] = r;
  } else if (wv == 1) {
    float r = 0.f;
#pragma unroll
    for (int q = 0; q < 16; ++q) r += redV[q][lane];
    TV[b*64 + lane] = r;
  }
}

// ============ K4: merged prefix + output (no PU/PV tables) ============
// block b: rows kk in [32b,32b+32); emits all i with kpos in [32b, 32b+32) (+8192 for b=255)
__global__ __launch_bounds__(256) void k_merge(
    const int* __restrict__ kpos, const int* __restrict__ inv,
    const int* __restrict__ inv1,
    const float* __restrict__ se1, const float* __restrict__ se1s,
    const float* __restrict__ Bs, const float* __restrict__ Es,
    const float* __restrict__ seq,
    const float* __restrict__ TU, const float* __restrict__ TV,
    float* __restrict__ out)
{
  __shared__ int kposl[NN];                       // 32 KB
  __shared__ float pu[33][64], pv[33][64];        // 16.5 KB
  __shared__ float redA[4][64], redB[4][64], redC[4][64];
  __shared__ int bnd[2];
  const int t = threadIdx.x, lane = t & 63, wv = t >> 6, b = blockIdx.x;
  for (int q = t; q < NN/4; q += 256)
    ((int4*)kposl)[q] = ((const int4*)kpos)[q];
  // base (chunks < b) and grand total of TU; base of TV
  float pbu = 0.f, pbv = 0.f, ptu = 0.f;
  for (int c = wv*64; c < wv*64 + 64; ++c) {
    const float tu = TU[c*64 + lane], tv = TV[c*64 + lane];
    ptu += tu;
    if (c < b) { pbu += tu; pbv += tv; }
  }
  redA[wv][lane] = pbu; redB[wv][lane] = pbv; redC[wv][lane] = ptu;
  __syncthreads();
  const float base_u = redA[0][lane]+redA[1][lane]+redA[2][lane]+redA[3][lane];
  const float base_v = redB[0][lane]+redB[1][lane]+redB[2][lane]+redB[3][lane];
  const float utot   = redC[0][lane]+redC[1][lane]+redC[2][lane]+redC[3][lane];
  // row contributions into pu[1..32]; pu[0]=0
  if (wv == 0) { pu[0][lane] = 0.f; pv[0][lane] = 0.f; }
  for (int s = wv; s < 32; s += 4) {
    const int kk = b*32 + s;
    const float sv = seq[(size_t)inv[kk]*OO + lane];
    pu[s+1][lane] = Bs[kk]*sv;
    pv[s+1][lane] = Es[kk]*sv;
  }
  if (t == 0) {   // emit range boundaries in descending kposl
    const int hi = 32*b + 32 + (b == 255 ? 1 : 0);
    int pos = 0;
    for (int s = NN; s; s >>= 1) { const int c = pos+s; if (c <= NN && kposl[c-1] >= hi) pos = c; }
    bnd[0] = pos;
    pos = 0;
    const int lo = 32*b;
    for (int s = NN; s; s >>= 1) { const int c = pos+s; if (c <= NN && kposl[c-1] >= lo) pos = c; }
    bnd[1] = pos;
  }
  __syncthreads();
  // tree scan: pu[m] = sum of rows 1..m (= exclusive prefix for local pos m)
  for (int d = 1; d < 32; d <<= 1) {
    float au[8], av[8];
#pragma unroll
    for (int q = 0; q < 8; ++q) {
      const int idx = t + q*256;
      const int mr = (idx >> 6) + 1, o = idx & 63;
      const int src = mr - d;
      au[q] = (src >= 0) ? pu[src][o] : 0.f;
      av[q] = (src >= 0) ? pv[src][o] : 0.f;
    }
    __syncthreads();
#pragma unroll
    for (int q = 0; q < 8; ++q) {
      const int idx = t + q*256;
      const int mr = (idx >> 6) + 1, o = idx & 63;
      pu[mr][o] += au[q]; pv[mr][o] += av[q];
    }
    __syncthreads();
  }
  // parallel emits
  const int r0 = bnd[0], r1 = bnd[1];
  for (int r = r0 + wv; r < r1; r += 4) {
    const int kl = kposl[r] - 32*b;
    const float e1v = se1[r], e1sv = se1s[r];
    const int i = inv1[r];
    const float ret = e1v*(utot - (base_u + pu[kl][lane]))
                    + e1sv*(base_v + pv[kl][lane]);
    out[(size_t)i*OO + lane] = (ret > 0.f) ? ret : expm1f(ret);
  }
}

extern "C" void kernel_launch(void* const* d_in, const int* in_sizes, int n_in,
                              void* d_out, int out_size, void* d_ws, size_t ws_size,
                              hipStream_t stream)
{
  (void)in_sizes; (void)n_in; (void)out_size; (void)ws_size;
  const float* x   = (const float*)d_in[0];
  const float* W1  = (const float*)d_in[1];
  const float* b1  = (const float*)d_in[2];
  const float* a1  = (const float*)d_in[3];
  const float* ba1 = (const float*)d_in[4];
  const float* a2  = (const float*)d_in[5];
  const float* ba2 = (const float*)d_in[6];
  float* out = (float*)d_out;

  float* w = (float*)d_ws;
  size_t off = 0;
  auto alloc = [&](size_t n) { float* p = w + off; off += (n + 63) & ~(size_t)63; return p; };
  float* seq  = alloc((size_t)NN*OO);
  float* f1   = alloc(NN);
  float* f2   = alloc(NN);
  float* E1   = alloc(NN);
  float* E1s  = alloc(NN);
  float* eF2  = alloc(NN);
  float* eF2s = alloc(NN);
  unsigned long long* keys = (unsigned long long*)alloc((size_t)4*NN);
  int*   inv1 = (int*)alloc(NN);
  int*   inv  = (int*)alloc(NN);
  float* s1   = alloc(NN);
  float* se1  = alloc(NN);
  float* se1s = alloc(NN);
  float* f2s  = alloc(NN);
  float* eF2srt  = alloc(NN);
  float* eF2ssrt = alloc(NN);
  float* Bs   = alloc(NN);
  float* Es   = alloc(NN);
  int*   kpos = (int*)alloc(NN);
  float* TU   = alloc(256*64);
  float* TV   = alloc(256*64);

  k_gemm<<<512, 256, 0, stream>>>(x, W1, b1, a1, ba1, a2, ba2,
                                  seq, f1, f2, E1, E1s, eF2, eF2s, keys);
  k_rank<<<256, 512, 0, stream>>>(keys, f1, E1, E1s, f2, eF2, eF2s,
                                  s1, se1, se1s, inv1, f2s, eF2srt, eF2ssrt, inv);
  k_DT<<<256, 1024, 0, stream>>>(se1, se1s, s1, f2, f2s, eF2srt, eF2ssrt,
                                 inv, seq, Bs, Es, kpos, TU, TV);
  k_merge<<<256, 256, 0, stream>>>(kpos, inv, inv1, se1, se1s, Bs, Es,
                                   seq, TU, TV, out);
}

// Round 10
// 74.208 us; speedup vs baseline: 1.0913x; 1.0913x over previous
//
#include <hip/hip_runtime.h>
#include <math.h>

#define NN 8192
#define CC 256
#define OO 64
#define JW 8      // j's per wave in k_rank

// ============ K1: GEMM (W1 -> LDS transposed) + f1/f2 + exp tables + sortable keys ============
__global__ __launch_bounds__(256) void k_gemm(
    const float* __restrict__ x, const float* __restrict__ W1,
    const float* __restrict__ b1, const float* __restrict__ a1,
    const float* __restrict__ ba1, const float* __restrict__ a2,
    const float* __restrict__ ba2,
    float* __restrict__ seq,
    float* __restrict__ f1, float* __restrict__ f2,
    float* __restrict__ E1, float* __restrict__ E1s,
    float* __restrict__ eF2, float* __restrict__ eF2s,
    unsigned long long* __restrict__ keys /* [2][NN] */)
{
  __shared__ float w_lds[64][66];
  const int t = threadIdx.x;
  const int p = t & 31;             // col pair: o = 2p, 2p+1
  const int g = t >> 5;             // 0..7 row group
  const int r0 = blockIdx.x*16 + g*2;
  const int r1 = r0 + 1;
  float c00 = 0.f, c01 = 0.f, c10 = 0.f, c11 = 0.f;
  for (int ct = 0; ct < 4; ++ct) {
    __syncthreads();
    for (int idx = t; idx < 4096; idx += 256) {
      const int o = idx >> 6, cc = idx & 63;
      w_lds[cc][o] = W1[o*CC + ct*64 + cc];
    }
    __syncthreads();
    const float* xr0 = x + (size_t)r0*CC + ct*64;
    const float* xr1 = x + (size_t)r1*CC + ct*64;
#pragma unroll 4
    for (int c = 0; c < 64; c += 4) {
      const float4 xa = *(const float4*)(xr0 + c);
      const float4 xb = *(const float4*)(xr1 + c);
      const float2 w0 = *(const float2*)&w_lds[c+0][2*p];
      const float2 w1 = *(const float2*)&w_lds[c+1][2*p];
      const float2 w2 = *(const float2*)&w_lds[c+2][2*p];
      const float2 w3 = *(const float2*)&w_lds[c+3][2*p];
      c00 = fmaf(xa.x, w0.x, c00); c00 = fmaf(xa.y, w1.x, c00);
      c00 = fmaf(xa.z, w2.x, c00); c00 = fmaf(xa.w, w3.x, c00);
      c01 = fmaf(xa.x, w0.y, c01); c01 = fmaf(xa.y, w1.y, c01);
      c01 = fmaf(xa.z, w2.y, c01); c01 = fmaf(xa.w, w3.y, c01);
      c10 = fmaf(xb.x, w0.x, c10); c10 = fmaf(xb.y, w1.x, c10);
      c10 = fmaf(xb.z, w2.x, c10); c10 = fmaf(xb.w, w3.x, c10);
      c11 = fmaf(xb.x, w0.y, c11); c11 = fmaf(xb.y, w1.y, c11);
      c11 = fmaf(xb.z, w2.y, c11); c11 = fmaf(xb.w, w3.y, c11);
    }
  }
  const float2 B2 = *(const float2*)&b1[2*p];
  const float v00 = c00 + B2.x, v01 = c01 + B2.y;
  const float v10 = c10 + B2.x, v11 = c11 + B2.y;
  *(float2*)&seq[(size_t)r0*OO + 2*p] = make_float2(v00, v01);
  *(float2*)&seq[(size_t)r1*OO + 2*p] = make_float2(v10, v11);
  const float2 A1 = *(const float2*)&a1[2*p];
  const float2 A2 = *(const float2*)&a2[2*p];
  float p1_0 = v00*A1.x + v01*A1.y;
  float p2_0 = v00*A2.x + v01*A2.y;
  float p1_1 = v10*A1.x + v11*A1.y;
  float p2_1 = v10*A2.x + v11*A2.y;
#pragma unroll
  for (int d = 1; d < 32; d <<= 1) {
    p1_0 += __shfl_xor(p1_0, d, 64);
    p2_0 += __shfl_xor(p2_0, d, 64);
    p1_1 += __shfl_xor(p1_1, d, 64);
    p2_1 += __shfl_xor(p2_1, d, 64);
  }
  if (p == 0) {
    const float bba1 = ba1[0], bba2 = ba2[0];
    const float t1a = p1_0 + bba1, t2a = p2_0 + bba2;
    const float t1b = p1_1 + bba1, t2b = p2_1 + bba2;
    f1[r0] = t1a; E1[r0] = expf(t1a); E1s[r0] = expf(0.01f*t1a);
    f2[r0] = t2a; eF2[r0] = expf(t2a); eF2s[r0] = expf(0.01f*t2a);
    f1[r1] = t1b; E1[r1] = expf(t1b); E1s[r1] = expf(0.01f*t1b);
    f2[r1] = t2b; eF2[r1] = expf(t2b); eF2s[r1] = expf(0.01f*t2b);
    unsigned u;
    u = __float_as_uint(t1a); u = (u & 0x80000000u) ? ~u : (u | 0x80000000u);
    keys[r0] = ((unsigned long long)u << 32) | (unsigned)r0;
    u = __float_as_uint(t1b); u = (u & 0x80000000u) ? ~u : (u | 0x80000000u);
    keys[r1] = ((unsigned long long)u << 32) | (unsigned)r1;
    u = __float_as_uint(t2a); u = (u & 0x80000000u) ? ~u : (u | 0x80000000u);
    keys[NN + r0] = ((unsigned long long)u << 32) | (unsigned)r0;
    u = __float_as_uint(t2b); u = (u & 0x80000000u) ? ~u : (u | 0x80000000u);
    keys[NN + r1] = ((unsigned long long)u << 32) | (unsigned)r1;
  }
}

// ============ K2: rank counting + sorted scatters (f1 side: +inv1; f2 side: +sorted exp tables) ============
__global__ __launch_bounds__(512) void k_rank(
    const unsigned long long* __restrict__ keys,
    const float* __restrict__ f1, const float* __restrict__ E1,
    const float* __restrict__ E1s, const float* __restrict__ f2,
    const float* __restrict__ eF2, const float* __restrict__ eF2s,
    float* __restrict__ s1, float* __restrict__ se1, float* __restrict__ se1s,
    int* __restrict__ inv1,
    float* __restrict__ f2s, float* __restrict__ eF2srt,
    float* __restrict__ eF2ssrt, int* __restrict__ inv)
{
  const int t = threadIdx.x;
  const int lane = t & 63, wv = t >> 6;        // 8 waves
  const int gw = blockIdx.x*8 + wv;            // 0..2047
  const int bj = gw*JW;
  const int arr = bj >> 13;                    // uniform per block
  const int jb = bj & (NN-1);
  const unsigned long long* kb = keys + ((size_t)arr << 13);
  unsigned long long K[JW];
#pragma unroll
  for (int q = 0; q < JW; ++q) {
    const unsigned long long kk = kb[jb + q];
    const unsigned lo = __builtin_amdgcn_readfirstlane((unsigned)kk);
    const unsigned hi = __builtin_amdgcn_readfirstlane((unsigned)(kk >> 32));
    K[q] = ((unsigned long long)hi << 32) | lo;
  }
  int cnt[JW];
#pragma unroll
  for (int q = 0; q < JW; ++q) cnt[q] = 0;
#pragma unroll 4
  for (int c = 0; c < NN/64; ++c) {
    const unsigned long long sk = kb[c*64 + lane];
#pragma unroll
    for (int q = 0; q < JW; ++q)
      cnt[q] += (sk < K[q]) ? 1 : 0;
  }
#pragma unroll
  for (int q = 0; q < JW; ++q) {
    int r = cnt[q];
#pragma unroll
    for (int d = 1; d < 64; d <<= 1) r += __shfl_xor(r, d, 64);
    if (lane == 0) {
      const int i = jb + q;
      if (arr == 0) {
        s1[r] = f1[i]; se1[r] = E1[i]; se1s[r] = E1s[i]; inv1[r] = i;
      } else {
        inv[r] = i; f2s[r] = f2[i]; eF2srt[r] = eF2[i]; eF2ssrt[r] = eF2s[i];
      }
    }
  }
}

// ============ K3: D-factors (kk-contiguous) + kpos via LDS binary search + TU/TV chunk totals ============
// grid 256 x 1024: block b owns sorted positions kk, r in [32b, 32b+32)
__global__ __launch_bounds__(1024) void k_DT(
    const float* __restrict__ se1, const float* __restrict__ se1s,
    const float* __restrict__ s1g,
    const float* __restrict__ f2s, const float* __restrict__ eF2srt,
    const float* __restrict__ eF2ssrt, const int* __restrict__ inv,
    const float* __restrict__ seq,
    float* __restrict__ Bs, float* __restrict__ Es,
    int* __restrict__ kpos, float* __restrict__ TU, float* __restrict__ TV)
{
  __shared__ float s1l[NN];          // 32 KB (sorted f1)
  __shared__ float f2sl[NN];         // 32 KB (sorted f2)
  __shared__ float csA[256], csB[256];
  __shared__ float csEA[257], csEB[257];
  __shared__ float bsl[32], esl[32];
  __shared__ float redU[16][64], redV[16][64];
  const int t = threadIdx.x;
  const int b = blockIdx.x;
  const float4 a0 = ((const float4*)se1 )[t*2];
  const float4 a1v = ((const float4*)se1 )[t*2+1];
  const float4 b0 = ((const float4*)se1s)[t*2];
  const float4 b1v = ((const float4*)se1s)[t*2+1];
  ((float4*)s1l)[t*2]   = ((const float4*)s1g)[t*2];
  ((float4*)s1l)[t*2+1] = ((const float4*)s1g)[t*2+1];
  ((float4*)f2sl)[t*2]   = ((const float4*)f2s)[t*2];
  ((float4*)f2sl)[t*2+1] = ((const float4*)f2s)[t*2+1];
  float sa = ((a0.x+a0.y)+(a0.z+a0.w)) + ((a1v.x+a1v.y)+(a1v.z+a1v.w));
  float sb = ((b0.x+b0.y)+(b0.z+b0.w)) + ((b1v.x+b1v.y)+(b1v.z+b1v.w));
  sa += __shfl_xor(sa, 1, 64); sb += __shfl_xor(sb, 1, 64);
  sa += __shfl_xor(sa, 2, 64); sb += __shfl_xor(sb, 2, 64);
  if ((t & 3) == 0) { csA[t>>2] = sa; csB[t>>2] = sb; }   // chunk(32) sums
  __syncthreads();
  for (int d = 1; d < 256; d <<= 1) {
    float pa = 0.f, pb = 0.f;
    if (t >= d && t < 256) { pa = csA[t-d]; pb = csB[t-d]; }
    __syncthreads();
    if (t < 256) { csA[t] += pa; csB[t] += pb; }
    __syncthreads();
  }
  if (t < 256) { csEA[t+1] = csA[t]; csEB[t+1] = csB[t]; }
  if (t == 0)  { csEA[0] = 0.f; csEB[0] = 0.f; }
  __syncthreads();
  const int wv = t >> 6, lane = t & 63;
  const int half = lane >> 5, m = lane & 31;
  // --- D part: kk-contiguous, sorted inputs ---
  {
    const int kk = b*32 + 2*wv + half;
    const float tgt = -f2sl[kk];
    int pos = 0;
#pragma unroll
    for (int s = NN; s; s >>= 1) {
      const int c = pos + s;
      if (c <= NN && s1l[c-1] < tgt) pos = c;
    }
    const int base = pos & ~31, cn = pos & 31;
    float ta = 0.f, tb = 0.f;
    if (m < cn) { ta = se1[base+m]; tb = se1s[base+m]; }
#pragma unroll
    for (int d = 1; d < 32; d <<= 1) {
      ta += __shfl_xor(ta, d, 64);
      tb += __shfl_xor(tb, d, 64);
    }
    if (m == 0) {
      const float PreA = csEA[pos>>5] + ta;
      const float PreB = csEB[pos>>5] + tb;
      const float T1 = csEA[256];
      const float e2 = eF2srt[kk], e2s = eF2ssrt[kk];
      const float D = fmaf(T1 - PreA, e2, PreB * e2s);
      const float bsv = e2 / D, esv = e2s / D;
      Bs[kk] = bsv; Es[kk] = esv;
      bsl[2*wv + half] = bsv; esl[2*wv + half] = esv;
    }
  }
  // --- kpos part: kpos[r] = #{ f2 < -s1[r] } via binary search in sorted f2 (LDS) ---
  if (t < 32) {
    const int r = b*32 + t;
    const float tgt = -s1l[r];
    int pos = 0;
#pragma unroll
    for (int s = NN; s; s >>= 1) {
      const int c = pos + s;
      if (c <= NN && f2sl[c-1] < tgt) pos = c;
    }
    kpos[r] = pos;
  }
  __syncthreads();
  // --- TU/TV: chunk b column totals from LDS factors ---
  {
    const int kk0 = b*32 + 2*wv, kk1 = kk0 + 1;
    const float s0v = seq[(size_t)inv[kk0]*OO + lane];
    const float s1v = seq[(size_t)inv[kk1]*OO + lane];
    redU[wv][lane] = bsl[2*wv]*s0v + bsl[2*wv+1]*s1v;
    redV[wv][lane] = esl[2*wv]*s0v + esl[2*wv+1]*s1v;
  }
  __syncthreads();
  if (wv == 0) {
    float r = 0.f;
#pragma unroll
    for (int q = 0; q < 16; ++q) r += redU[q][lane];
    TU[b*64 + lane] = r;
  } else if (wv == 1) {
    float r = 0.f;
#pragma unroll
    for (int q = 0; q < 16; ++q) r += redV[q][lane];
    TV[b*64 + lane] = r;
  }
}

// ============ K4: merged prefix + output (no PU/PV tables) ============
// block b: rows kk in [32b,32b+32); emits all i with kpos in [32b, 32b+32) (+8192 for b=255)
__global__ __launch_bounds__(256) void k_merge(
    const int* __restrict__ kpos, const int* __restrict__ inv,
    const int* __restrict__ inv1,
    const float* __restrict__ se1, const float* __restrict__ se1s,
    const float* __restrict__ Bs, const float* __restrict__ Es,
    const float* __restrict__ seq,
    const float* __restrict__ TU, const float* __restrict__ TV,
    float* __restrict__ out)
{
  __shared__ int kposl[NN];                       // 32 KB
  __shared__ float pu[33][64], pv[33][64];        // 16.5 KB
  __shared__ float redA[4][64], redB[4][64], redC[4][64];
  __shared__ int bnd[2];
  const int t = threadIdx.x, lane = t & 63, wv = t >> 6, b = blockIdx.x;
  for (int q = t; q < NN/4; q += 256)
    ((int4*)kposl)[q] = ((const int4*)kpos)[q];
  // base (chunks < b) and grand total of TU; base of TV
  float pbu = 0.f, pbv = 0.f, ptu = 0.f;
  for (int c = wv*64; c < wv*64 + 64; ++c) {
    const float tu = TU[c*64 + lane], tv = TV[c*64 + lane];
    ptu += tu;
    if (c < b) { pbu += tu; pbv += tv; }
  }
  redA[wv][lane] = pbu; redB[wv][lane] = pbv; redC[wv][lane] = ptu;
  __syncthreads();
  const float base_u = redA[0][lane]+redA[1][lane]+redA[2][lane]+redA[3][lane];
  const float base_v = redB[0][lane]+redB[1][lane]+redB[2][lane]+redB[3][lane];
  const float utot   = redC[0][lane]+redC[1][lane]+redC[2][lane]+redC[3][lane];
  // row contributions into pu[1..32]; pu[0]=0
  if (wv == 0) { pu[0][lane] = 0.f; pv[0][lane] = 0.f; }
  for (int s = wv; s < 32; s += 4) {
    const int kk = b*32 + s;
    const float sv = seq[(size_t)inv[kk]*OO + lane];
    pu[s+1][lane] = Bs[kk]*sv;
    pv[s+1][lane] = Es[kk]*sv;
  }
  if (t == 0) {   // emit range boundaries in descending kposl
    const int hi = 32*b + 32 + (b == 255 ? 1 : 0);
    int pos = 0;
    for (int s = NN; s; s >>= 1) { const int c = pos+s; if (c <= NN && kposl[c-1] >= hi) pos = c; }
    bnd[0] = pos;
    pos = 0;
    const int lo = 32*b;
    for (int s = NN; s; s >>= 1) { const int c = pos+s; if (c <= NN && kposl[c-1] >= lo) pos = c; }
    bnd[1] = pos;
  }
  __syncthreads();
  // tree scan: pu[m] = sum of rows 1..m (= exclusive prefix for local pos m)
  for (int d = 1; d < 32; d <<= 1) {
    float au[8], av[8];
#pragma unroll
    for (int q = 0; q < 8; ++q) {
      const int idx = t + q*256;
      const int mr = (idx >> 6) + 1, o = idx & 63;
      const int src = mr - d;
      au[q] = (src >= 0) ? pu[src][o] : 0.f;
      av[q] = (src >= 0) ? pv[src][o] : 0.f;
    }
    __syncthreads();
#pragma unroll
    for (int q = 0; q < 8; ++q) {
      const int idx = t + q*256;
      const int mr = (idx >> 6) + 1, o = idx & 63;
      pu[mr][o] += au[q]; pv[mr][o] += av[q];
    }
    __syncthreads();
  }
  // parallel emits
  const int r0 = bnd[0], r1 = bnd[1];
  for (int r = r0 + wv; r < r1; r += 4) {
    const int kl = kposl[r] - 32*b;
    const float e1v = se1[r], e1sv = se1s[r];
    const int i = inv1[r];
    const float ret = e1v*(utot - (base_u + pu[kl][lane]))
                    + e1sv*(base_v + pv[kl][lane]);
    out[(size_t)i*OO + lane] = (ret > 0.f) ? ret : expm1f(ret);
  }
}

extern "C" void kernel_launch(void* const* d_in, const int* in_sizes, int n_in,
                              void* d_out, int out_size, void* d_ws, size_t ws_size,
                              hipStream_t stream)
{
  (void)in_sizes; (void)n_in; (void)out_size; (void)ws_size;
  const float* x   = (const float*)d_in[0];
  const float* W1  = (const float*)d_in[1];
  const float* b1  = (const float*)d_in[2];
  const float* a1  = (const float*)d_in[3];
  const float* ba1 = (const float*)d_in[4];
  const float* a2  = (const float*)d_in[5];
  const float* ba2 = (const float*)d_in[6];
  float* out = (float*)d_out;

  float* w = (float*)d_ws;
  size_t off = 0;
  auto alloc = [&](size_t n) { float* p = w + off; off += (n + 63) & ~(size_t)63; return p; };
  float* seq  = alloc((size_t)NN*OO);
  float* f1   = alloc(NN);
  float* f2   = alloc(NN);
  float* E1   = alloc(NN);
  float* E1s  = alloc(NN);
  float* eF2  = alloc(NN);
  float* eF2s = alloc(NN);
  unsigned long long* keys = (unsigned long long*)alloc((size_t)4*NN);
  int*   inv1 = (int*)alloc(NN);
  int*   inv  = (int*)alloc(NN);
  float* s1   = alloc(NN);
  float* se1  = alloc(NN);
  float* se1s = alloc(NN);
  float* f2s  = alloc(NN);
  float* eF2srt  = alloc(NN);
  float* eF2ssrt = alloc(NN);
  float* Bs   = alloc(NN);
  float* Es   = alloc(NN);
  int*   kpos = (int*)alloc(NN);
  float* TU   = alloc(256*64);
  float* TV   = alloc(256*64);

  k_gemm<<<512, 256, 0, stream>>>(x, W1, b1, a1, ba1, a2, ba2,
                                  seq, f1, f2, E1, E1s, eF2, eF2s, keys);
  k_rank<<<256, 512, 0, stream>>>(keys, f1, E1, E1s, f2, eF2, eF2s,
                                  s1, se1, se1s, inv1, f2s, eF2srt, eF2ssrt, inv);
  k_DT<<<256, 1024, 0, stream>>>(se1, se1s, s1, f2s, eF2srt, eF2ssrt,
                                 inv, seq, Bs, Es, kpos, TU, TV);
  k_merge<<<256, 256, 0, stream>>>(kpos, inv, inv1, se1, se1s, Bs, Es,
                                   seq, TU, TV, out);
}

// Round 11
// 68.281 us; speedup vs baseline: 1.1860x; 1.0868x over previous
//
#include <hip/hip_runtime.h>
#include <math.h>

#define NN 8192
#define CC 256
#define OO 64
#define JW 8      // j's per wave in k_rank

// ============ K1: GEMM (W1 -> LDS transposed) + f1/f2 + exp tables + sortable keys ============
__global__ __launch_bounds__(256) void k_gemm(
    const float* __restrict__ x, const float* __restrict__ W1,
    const float* __restrict__ b1, const float* __restrict__ a1,
    const float* __restrict__ ba1, const float* __restrict__ a2,
    const float* __restrict__ ba2,
    float* __restrict__ seq,
    float* __restrict__ f1, float* __restrict__ f2,
    float* __restrict__ E1, float* __restrict__ E1s,
    float* __restrict__ eF2, float* __restrict__ eF2s,
    unsigned long long* __restrict__ keys /* [2][NN] */)
{
  __shared__ float w_lds[64][66];
  const int t = threadIdx.x;
  const int p = t & 31;             // col pair: o = 2p, 2p+1
  const int g = t >> 5;             // 0..7 row group
  const int r0 = blockIdx.x*16 + g*2;
  const int r1 = r0 + 1;
  float c00 = 0.f, c01 = 0.f, c10 = 0.f, c11 = 0.f;
  for (int ct = 0; ct < 4; ++ct) {
    __syncthreads();
    for (int idx = t; idx < 4096; idx += 256) {
      const int o = idx >> 6, cc = idx & 63;
      w_lds[cc][o] = W1[o*CC + ct*64 + cc];
    }
    __syncthreads();
    const float* xr0 = x + (size_t)r0*CC + ct*64;
    const float* xr1 = x + (size_t)r1*CC + ct*64;
#pragma unroll 4
    for (int c = 0; c < 64; c += 4) {
      const float4 xa = *(const float4*)(xr0 + c);
      const float4 xb = *(const float4*)(xr1 + c);
      const float2 w0 = *(const float2*)&w_lds[c+0][2*p];
      const float2 w1 = *(const float2*)&w_lds[c+1][2*p];
      const float2 w2 = *(const float2*)&w_lds[c+2][2*p];
      const float2 w3 = *(const float2*)&w_lds[c+3][2*p];
      c00 = fmaf(xa.x, w0.x, c00); c00 = fmaf(xa.y, w1.x, c00);
      c00 = fmaf(xa.z, w2.x, c00); c00 = fmaf(xa.w, w3.x, c00);
      c01 = fmaf(xa.x, w0.y, c01); c01 = fmaf(xa.y, w1.y, c01);
      c01 = fmaf(xa.z, w2.y, c01); c01 = fmaf(xa.w, w3.y, c01);
      c10 = fmaf(xb.x, w0.x, c10); c10 = fmaf(xb.y, w1.x, c10);
      c10 = fmaf(xb.z, w2.x, c10); c10 = fmaf(xb.w, w3.x, c10);
      c11 = fmaf(xb.x, w0.y, c11); c11 = fmaf(xb.y, w1.y, c11);
      c11 = fmaf(xb.z, w2.y, c11); c11 = fmaf(xb.w, w3.y, c11);
    }
  }
  const float2 B2 = *(const float2*)&b1[2*p];
  const float v00 = c00 + B2.x, v01 = c01 + B2.y;
  const float v10 = c10 + B2.x, v11 = c11 + B2.y;
  *(float2*)&seq[(size_t)r0*OO + 2*p] = make_float2(v00, v01);
  *(float2*)&seq[(size_t)r1*OO + 2*p] = make_float2(v10, v11);
  const float2 A1 = *(const float2*)&a1[2*p];
  const float2 A2 = *(const float2*)&a2[2*p];
  float p1_0 = v00*A1.x + v01*A1.y;
  float p2_0 = v00*A2.x + v01*A2.y;
  float p1_1 = v10*A1.x + v11*A1.y;
  float p2_1 = v10*A2.x + v11*A2.y;
#pragma unroll
  for (int d = 1; d < 32; d <<= 1) {
    p1_0 += __shfl_xor(p1_0, d, 64);
    p2_0 += __shfl_xor(p2_0, d, 64);
    p1_1 += __shfl_xor(p1_1, d, 64);
    p2_1 += __shfl_xor(p2_1, d, 64);
  }
  if (p == 0) {
    const float bba1 = ba1[0], bba2 = ba2[0];
    const float t1a = p1_0 + bba1, t2a = p2_0 + bba2;
    const float t1b = p1_1 + bba1, t2b = p2_1 + bba2;
    f1[r0] = t1a; E1[r0] = expf(t1a); E1s[r0] = expf(0.01f*t1a);
    f2[r0] = t2a; eF2[r0] = expf(t2a); eF2s[r0] = expf(0.01f*t2a);
    f1[r1] = t1b; E1[r1] = expf(t1b); E1s[r1] = expf(0.01f*t1b);
    f2[r1] = t2b; eF2[r1] = expf(t2b); eF2s[r1] = expf(0.01f*t2b);
    unsigned u;
    u = __float_as_uint(t1a); u = (u & 0x80000000u) ? ~u : (u | 0x80000000u);
    keys[r0] = ((unsigned long long)u << 32) | (unsigned)r0;
    u = __float_as_uint(t1b); u = (u & 0x80000000u) ? ~u : (u | 0x80000000u);
    keys[r1] = ((unsigned long long)u << 32) | (unsigned)r1;
    u = __float_as_uint(t2a); u = (u & 0x80000000u) ? ~u : (u | 0x80000000u);
    keys[NN + r0] = ((unsigned long long)u << 32) | (unsigned)r0;
    u = __float_as_uint(t2b); u = (u & 0x80000000u) ? ~u : (u | 0x80000000u);
    keys[NN + r1] = ((unsigned long long)u << 32) | (unsigned)r1;
  }
}

// ============ K2: rank counting from LDS-staged keys + sorted scatters ============
// grid 256 x 512: block stages its key array (64 KB) in LDS; wave wv owns 8 j's
__global__ __launch_bounds__(512) void k_rank(
    const unsigned long long* __restrict__ keys,
    const float* __restrict__ f1, const float* __restrict__ E1,
    const float* __restrict__ E1s, const float* __restrict__ f2,
    const float* __restrict__ eF2, const float* __restrict__ eF2s,
    float* __restrict__ s1, float* __restrict__ se1, float* __restrict__ se1s,
    float* __restrict__ f2s, float* __restrict__ eF2srt,
    float* __restrict__ eF2ssrt, int* __restrict__ inv)
{
  __shared__ unsigned long long skl[NN];   // 64 KB
  const int t = threadIdx.x;
  const int lane = t & 63, wv = t >> 6;    // 8 waves
  const int gw = blockIdx.x*8 + wv;        // 0..2047
  const int bj = gw*JW;
  const int arr = bj >> 13;                // uniform per block (64-j aligned)
  const int jb = bj & (NN-1);
  const unsigned long long* kb = keys + ((size_t)arr << 13);
  for (int q = t; q < NN/2; q += 512)
    ((ulonglong2*)skl)[q] = ((const ulonglong2*)kb)[q];
  __syncthreads();
  unsigned long long K[JW];
#pragma unroll
  for (int q = 0; q < JW; ++q) {
    const unsigned long long kk = skl[jb + q];   // wave-uniform LDS addr -> broadcast
    const unsigned lo = __builtin_amdgcn_readfirstlane((unsigned)kk);
    const unsigned hi = __builtin_amdgcn_readfirstlane((unsigned)(kk >> 32));
    K[q] = ((unsigned long long)hi << 32) | lo;
  }
  int cnt[JW];
#pragma unroll
  for (int q = 0; q < JW; ++q) cnt[q] = 0;
#pragma unroll 4
  for (int c = 0; c < NN/64; ++c) {
    const unsigned long long sk = skl[c*64 + lane];   // per-lane, conflict-free
#pragma unroll
    for (int q = 0; q < JW; ++q)
      cnt[q] += (sk < K[q]) ? 1 : 0;
  }
#pragma unroll
  for (int q = 0; q < JW; ++q) {
    int r = cnt[q];
#pragma unroll
    for (int d = 1; d < 64; d <<= 1) r += __shfl_xor(r, d, 64);
    if (lane == 0) {
      const int i = jb + q;
      if (arr == 0) {
        s1[r] = f1[i]; se1[r] = E1[i]; se1s[r] = E1s[i];
      } else {
        inv[r] = i; f2s[r] = f2[i]; eF2srt[r] = eF2[i]; eF2ssrt[r] = eF2s[i];
      }
    }
  }
}

// ============ K3: D-factors (kk-contiguous, sorted inputs) + TU/TV chunk totals ============
// grid 256 x 1024: block b owns sorted positions kk in [32b, 32b+32)
__global__ __launch_bounds__(1024) void k_DT(
    const float* __restrict__ se1, const float* __restrict__ se1s,
    const float* __restrict__ s1g,
    const float* __restrict__ f2s, const float* __restrict__ eF2srt,
    const float* __restrict__ eF2ssrt, const int* __restrict__ inv,
    const float* __restrict__ seq,
    float* __restrict__ Bs, float* __restrict__ Es,
    float* __restrict__ TU, float* __restrict__ TV)
{
  __shared__ float s1l[NN];          // 32 KB (sorted f1)
  __shared__ float csA[256], csB[256];
  __shared__ float csEA[257], csEB[257];
  __shared__ float bsl[32], esl[32];
  __shared__ float redU[16][64], redV[16][64];
  const int t = threadIdx.x;
  const int b = blockIdx.x;
  const float4 a0 = ((const float4*)se1 )[t*2];
  const float4 a1v = ((const float4*)se1 )[t*2+1];
  const float4 b0 = ((const float4*)se1s)[t*2];
  const float4 b1v = ((const float4*)se1s)[t*2+1];
  ((float4*)s1l)[t*2]   = ((const float4*)s1g)[t*2];
  ((float4*)s1l)[t*2+1] = ((const float4*)s1g)[t*2+1];
  float sa = ((a0.x+a0.y)+(a0.z+a0.w)) + ((a1v.x+a1v.y)+(a1v.z+a1v.w));
  float sb = ((b0.x+b0.y)+(b0.z+b0.w)) + ((b1v.x+b1v.y)+(b1v.z+b1v.w));
  sa += __shfl_xor(sa, 1, 64); sb += __shfl_xor(sb, 1, 64);
  sa += __shfl_xor(sa, 2, 64); sb += __shfl_xor(sb, 2, 64);
  if ((t & 3) == 0) { csA[t>>2] = sa; csB[t>>2] = sb; }   // chunk(32) sums
  __syncthreads();
  for (int d = 1; d < 256; d <<= 1) {
    float pa = 0.f, pb = 0.f;
    if (t >= d && t < 256) { pa = csA[t-d]; pb = csB[t-d]; }
    __syncthreads();
    if (t < 256) { csA[t] += pa; csB[t] += pb; }
    __syncthreads();
  }
  if (t < 256) { csEA[t+1] = csA[t]; csEB[t+1] = csB[t]; }
  if (t == 0)  { csEA[0] = 0.f; csEB[0] = 0.f; }
  __syncthreads();
  const int wv = t >> 6, lane = t & 63;
  const int half = lane >> 5, m = lane & 31;
  // --- D part ---
  {
    const int kk = b*32 + 2*wv + half;
    const float tgt = -f2s[kk];
    int pos = 0;
#pragma unroll
    for (int s = NN; s; s >>= 1) {
      const int c = pos + s;
      if (c <= NN && s1l[c-1] < tgt) pos = c;
    }
    const int base = pos & ~31, cn = pos & 31;
    float ta = 0.f, tb = 0.f;
    if (m < cn) { ta = se1[base+m]; tb = se1s[base+m]; }
#pragma unroll
    for (int d = 1; d < 32; d <<= 1) {
      ta += __shfl_xor(ta, d, 64);
      tb += __shfl_xor(tb, d, 64);
    }
    if (m == 0) {
      const float PreA = csEA[pos>>5] + ta;
      const float PreB = csEB[pos>>5] + tb;
      const float T1 = csEA[256];
      const float e2 = eF2srt[kk], e2s = eF2ssrt[kk];
      const float D = fmaf(T1 - PreA, e2, PreB * e2s);
      const float bsv = e2 / D, esv = e2s / D;
      Bs[kk] = bsv; Es[kk] = esv;
      bsl[2*wv + half] = bsv; esl[2*wv + half] = esv;
    }
  }
  __syncthreads();
  // --- TU/TV: chunk b column totals from LDS factors ---
  {
    const int kk0 = b*32 + 2*wv, kk1 = kk0 + 1;
    const float s0v = seq[(size_t)inv[kk0]*OO + lane];
    const float s1v = seq[(size_t)inv[kk1]*OO + lane];
    redU[wv][lane] = bsl[2*wv]*s0v + bsl[2*wv+1]*s1v;
    redV[wv][lane] = esl[2*wv]*s0v + esl[2*wv+1]*s1v;
  }
  __syncthreads();
  if (wv == 0) {
    float r = 0.f;
#pragma unroll
    for (int q = 0; q < 16; ++q) r += redU[q][lane];
    TU[b*64 + lane] = r;
  } else if (wv == 1) {
    float r = 0.f;
#pragma unroll
    for (int q = 0; q < 16; ++q) r += redV[q][lane];
    TV[b*64 + lane] = r;
  }
}

// ============ K4: PU/PV prefix rows; base-prefix parallelized over 4 waves ============ grid 256 x 256
__global__ __launch_bounds__(256) void k_apply(
    const float* __restrict__ seq, const int* __restrict__ inv,
    const float* __restrict__ Bs, const float* __restrict__ Es,
    const float* __restrict__ TU, const float* __restrict__ TV,
    float* __restrict__ PU, float* __restrict__ PV)
{
  __shared__ float bU[4][64], bV[4][64];
  const int b = blockIdx.x, t = threadIdx.x;
  const int wv = t >> 6, o = t & 63;
  float pu = 0.f, pv = 0.f;
  for (int c = wv; c < b; c += 4) {
    pu += TU[c*64 + o];
    pv += TV[c*64 + o];
  }
  bU[wv][o] = pu; bV[wv][o] = pv;
  __syncthreads();
  if (wv < 2) {
    const float* __restrict__ S = wv ? Es : Bs;
    float* __restrict__ dst     = wv ? PV : PU;
    const float (*bb)[64] = wv ? bV : bU;
    float r = bb[0][o] + bb[1][o] + bb[2][o] + bb[3][o];
#pragma unroll 4
    for (int k = 0; k < 32; ++k) {
      const int kk = b*32 + k;
      dst[(size_t)kk*OO + o] = r;
      r = fmaf(S[kk], seq[(size_t)inv[kk]*OO + o], r);
    }
    if (b == 255) dst[(size_t)NN*OO + o] = r;   // grand total row
  }
}

// ============ K5: final combine + ELU (search in LDS-staged f2s) ============ grid 256 x 1024
__global__ __launch_bounds__(1024) void k_final(
    const float* __restrict__ f1, const float* __restrict__ E1,
    const float* __restrict__ E1s, const float* __restrict__ f2s,
    const float* __restrict__ PU, const float* __restrict__ PV,
    float* __restrict__ out)
{
  __shared__ float f2sl[NN];
  const int t = threadIdx.x;
  ((float4*)f2sl)[t*2]   = ((const float4*)f2s)[t*2];
  ((float4*)f2sl)[t*2+1] = ((const float4*)f2s)[t*2+1];
  __syncthreads();
  const int wv = t >> 6, lane = t & 63;
  const float utot = PU[(size_t)NN*OO + lane];
#pragma unroll
  for (int rr = 0; rr < 2; ++rr) {
    const int i = blockIdx.x*32 + 2*wv + rr;
    const float tgt = -f1[i];
    int pos = 0;
#pragma unroll
    for (int s = NN; s; s >>= 1) {
      const int c = pos + s;
      if (c <= NN && f2sl[c-1] < tgt) pos = c;
    }
    const float pu = PU[(size_t)pos*OO + lane];
    const float pv = PV[(size_t)pos*OO + lane];
    const float ret = E1[i]*(utot - pu) + E1s[i]*pv;
    out[(size_t)i*OO + lane] = (ret > 0.f) ? ret : expm1f(ret);
  }
}

extern "C" void kernel_launch(void* const* d_in, const int* in_sizes, int n_in,
                              void* d_out, int out_size, void* d_ws, size_t ws_size,
                              hipStream_t stream)
{
  (void)in_sizes; (void)n_in; (void)out_size; (void)ws_size;
  const float* x   = (const float*)d_in[0];
  const float* W1  = (const float*)d_in[1];
  const float* b1  = (const float*)d_in[2];
  const float* a1  = (const float*)d_in[3];
  const float* ba1 = (const float*)d_in[4];
  const float* a2  = (const float*)d_in[5];
  const float* ba2 = (const float*)d_in[6];
  float* out = (float*)d_out;

  float* w = (float*)d_ws;
  size_t off = 0;
  auto alloc = [&](size_t n) { float* p = w + off; off += (n + 63) & ~(size_t)63; return p; };
  float* seq  = alloc((size_t)NN*OO);
  float* f1   = alloc(NN);
  float* f2   = alloc(NN);
  float* E1   = alloc(NN);
  float* E1s  = alloc(NN);
  float* eF2  = alloc(NN);
  float* eF2s = alloc(NN);
  unsigned long long* keys = (unsigned long long*)alloc((size_t)4*NN);
  int*   inv  = (int*)alloc(NN);
  float* s1   = alloc(NN);
  float* se1  = alloc(NN);
  float* se1s = alloc(NN);
  float* f2s  = alloc(NN);
  float* eF2srt  = alloc(NN);
  float* eF2ssrt = alloc(NN);
  float* Bs   = alloc(NN);
  float* Es   = alloc(NN);
  float* TU   = alloc(256*64);
  float* TV   = alloc(256*64);
  float* PU   = alloc((size_t)(NN+1)*OO);
  float* PV   = alloc((size_t)(NN+1)*OO);

  k_gemm<<<512, 256, 0, stream>>>(x, W1, b1, a1, ba1, a2, ba2,
                                  seq, f1, f2, E1, E1s, eF2, eF2s, keys);
  k_rank<<<256, 512, 0, stream>>>(keys, f1, E1, E1s, f2, eF2, eF2s,
                                  s1, se1, se1s, f2s, eF2srt, eF2ssrt, inv);
  k_DT<<<256, 1024, 0, stream>>>(se1, se1s, s1, f2s, eF2srt, eF2ssrt,
                                 inv, seq, Bs, Es, TU, TV);
  k_apply<<<256, 256, 0, stream>>>(seq, inv, Bs, Es, TU, TV, PU, PV);
  k_final<<<256, 1024, 0, stream>>>(f1, E1, E1s, f2s, PU, PV, out);
}

// Round 12
// 55.440 us; speedup vs baseline: 1.4607x; 1.2316x over previous
//
#include <hip/hip_runtime.h>
#include <math.h>

#define NN 8192
#define CC 256
#define OO 64
#define JW 8      // j's per wave in k_rank

// ============ K1: GEMM (W1 -> LDS transposed) + f1/f2 + exp tables + sortable keys ============
__global__ __launch_bounds__(256) void k_gemm(
    const float* __restrict__ x, const float* __restrict__ W1,
    const float* __restrict__ b1, const float* __restrict__ a1,
    const float* __restrict__ ba1, const float* __restrict__ a2,
    const float* __restrict__ ba2,
    float* __restrict__ seq,
    float* __restrict__ f1, float* __restrict__ f2,
    float* __restrict__ E1, float* __restrict__ E1s,
    float* __restrict__ eF2, float* __restrict__ eF2s,
    unsigned long long* __restrict__ keys /* [2][NN] */)
{
  __shared__ float w_lds[64][66];
  const int t = threadIdx.x;
  const int p = t & 31;             // col pair: o = 2p, 2p+1
  const int g = t >> 5;             // 0..7 row group
  const int r0 = blockIdx.x*16 + g*2;
  const int r1 = r0 + 1;
  float c00 = 0.f, c01 = 0.f, c10 = 0.f, c11 = 0.f;
  for (int ct = 0; ct < 4; ++ct) {
    __syncthreads();
    for (int idx = t; idx < 4096; idx += 256) {
      const int o = idx >> 6, cc = idx & 63;
      w_lds[cc][o] = W1[o*CC + ct*64 + cc];
    }
    __syncthreads();
    const float* xr0 = x + (size_t)r0*CC + ct*64;
    const float* xr1 = x + (size_t)r1*CC + ct*64;
#pragma unroll 4
    for (int c = 0; c < 64; c += 4) {
      const float4 xa = *(const float4*)(xr0 + c);
      const float4 xb = *(const float4*)(xr1 + c);
      const float2 w0 = *(const float2*)&w_lds[c+0][2*p];
      const float2 w1 = *(const float2*)&w_lds[c+1][2*p];
      const float2 w2 = *(const float2*)&w_lds[c+2][2*p];
      const float2 w3 = *(const float2*)&w_lds[c+3][2*p];
      c00 = fmaf(xa.x, w0.x, c00); c00 = fmaf(xa.y, w1.x, c00);
      c00 = fmaf(xa.z, w2.x, c00); c00 = fmaf(xa.w, w3.x, c00);
      c01 = fmaf(xa.x, w0.y, c01); c01 = fmaf(xa.y, w1.y, c01);
      c01 = fmaf(xa.z, w2.y, c01); c01 = fmaf(xa.w, w3.y, c01);
      c10 = fmaf(xb.x, w0.x, c10); c10 = fmaf(xb.y, w1.x, c10);
      c10 = fmaf(xb.z, w2.x, c10); c10 = fmaf(xb.w, w3.x, c10);
      c11 = fmaf(xb.x, w0.y, c11); c11 = fmaf(xb.y, w1.y, c11);
      c11 = fmaf(xb.z, w2.y, c11); c11 = fmaf(xb.w, w3.y, c11);
    }
  }
  const float2 B2 = *(const float2*)&b1[2*p];
  const float v00 = c00 + B2.x, v01 = c01 + B2.y;
  const float v10 = c10 + B2.x, v11 = c11 + B2.y;
  *(float2*)&seq[(size_t)r0*OO + 2*p] = make_float2(v00, v01);
  *(float2*)&seq[(size_t)r1*OO + 2*p] = make_float2(v10, v11);
  const float2 A1 = *(const float2*)&a1[2*p];
  const float2 A2 = *(const float2*)&a2[2*p];
  float p1_0 = v00*A1.x + v01*A1.y;
  float p2_0 = v00*A2.x + v01*A2.y;
  float p1_1 = v10*A1.x + v11*A1.y;
  float p2_1 = v10*A2.x + v11*A2.y;
#pragma unroll
  for (int d = 1; d < 32; d <<= 1) {
    p1_0 += __shfl_xor(p1_0, d, 64);
    p2_0 += __shfl_xor(p2_0, d, 64);
    p1_1 += __shfl_xor(p1_1, d, 64);
    p2_1 += __shfl_xor(p2_1, d, 64);
  }
  if (p == 0) {
    const float bba1 = ba1[0], bba2 = ba2[0];
    const float t1a = p1_0 + bba1, t2a = p2_0 + bba2;
    const float t1b = p1_1 + bba1, t2b = p2_1 + bba2;
    f1[r0] = t1a; E1[r0] = expf(t1a); E1s[r0] = expf(0.01f*t1a);
    f2[r0] = t2a; eF2[r0] = expf(t2a); eF2s[r0] = expf(0.01f*t2a);
    f1[r1] = t1b; E1[r1] = expf(t1b); E1s[r1] = expf(0.01f*t1b);
    f2[r1] = t2b; eF2[r1] = expf(t2b); eF2s[r1] = expf(0.01f*t2b);
    unsigned u;
    u = __float_as_uint(t1a); u = (u & 0x80000000u) ? ~u : (u | 0x80000000u);
    keys[r0] = ((unsigned long long)u << 32) | (unsigned)r0;
    u = __float_as_uint(t1b); u = (u & 0x80000000u) ? ~u : (u | 0x80000000u);
    keys[r1] = ((unsigned long long)u << 32) | (unsigned)r1;
    u = __float_as_uint(t2a); u = (u & 0x80000000u) ? ~u : (u | 0x80000000u);
    keys[NN + r0] = ((unsigned long long)u << 32) | (unsigned)r0;
    u = __float_as_uint(t2b); u = (u & 0x80000000u) ? ~u : (u | 0x80000000u);
    keys[NN + r1] = ((unsigned long long)u << 32) | (unsigned)r1;
  }
}

// ============ K2: rank counting from LDS-staged keys + sorted scatters ============
__global__ __launch_bounds__(512) void k_rank(
    const unsigned long long* __restrict__ keys,
    const float* __restrict__ f1, const float* __restrict__ E1,
    const float* __restrict__ E1s, const float* __restrict__ f2,
    const float* __restrict__ eF2, const float* __restrict__ eF2s,
    float* __restrict__ s1, float* __restrict__ se1, float* __restrict__ se1s,
    float* __restrict__ f2s, float* __restrict__ eF2srt,
    float* __restrict__ eF2ssrt, int* __restrict__ inv)
{
  __shared__ unsigned long long skl[NN];   // 64 KB
  const int t = threadIdx.x;
  const int lane = t & 63, wv = t >> 6;    // 8 waves
  const int gw = blockIdx.x*8 + wv;        // 0..2047
  const int bj = gw*JW;
  const int arr = bj >> 13;                // uniform per block (64-j aligned)
  const int jb = bj & (NN-1);
  const unsigned long long* kb = keys + ((size_t)arr << 13);
  for (int q = t; q < NN/2; q += 512)
    ((ulonglong2*)skl)[q] = ((const ulonglong2*)kb)[q];
  __syncthreads();
  unsigned long long K[JW];
#pragma unroll
  for (int q = 0; q < JW; ++q) {
    const unsigned long long kk = skl[jb + q];
    const unsigned lo = __builtin_amdgcn_readfirstlane((unsigned)kk);
    const unsigned hi = __builtin_amdgcn_readfirstlane((unsigned)(kk >> 32));
    K[q] = ((unsigned long long)hi << 32) | lo;
  }
  int cnt[JW];
#pragma unroll
  for (int q = 0; q < JW; ++q) cnt[q] = 0;
#pragma unroll 4
  for (int c = 0; c < NN/64; ++c) {
    const unsigned long long sk = skl[c*64 + lane];
#pragma unroll
    for (int q = 0; q < JW; ++q)
      cnt[q] += (sk < K[q]) ? 1 : 0;
  }
#pragma unroll
  for (int q = 0; q < JW; ++q) {
    int r = cnt[q];
#pragma unroll
    for (int d = 1; d < 64; d <<= 1) r += __shfl_xor(r, d, 64);
    if (lane == 0) {
      const int i = jb + q;
      if (arr == 0) {
        s1[r] = f1[i]; se1[r] = E1[i]; se1s[r] = E1s[i];
      } else {
        inv[r] = i; f2s[r] = f2[i]; eF2srt[r] = eF2[i]; eF2ssrt[r] = eF2s[i];
      }
    }
  }
}

// ============ K3: D-factors (kk-contiguous, sorted inputs) + TU/TV chunk totals ============
__global__ __launch_bounds__(1024) void k_DT(
    const float* __restrict__ se1, const float* __restrict__ se1s,
    const float* __restrict__ s1g,
    const float* __restrict__ f2s, const float* __restrict__ eF2srt,
    const float* __restrict__ eF2ssrt, const int* __restrict__ inv,
    const float* __restrict__ seq,
    float* __restrict__ Bs, float* __restrict__ Es,
    float* __restrict__ TU, float* __restrict__ TV)
{
  __shared__ float s1l[NN];          // 32 KB (sorted f1)
  __shared__ float csA[256], csB[256];
  __shared__ float csEA[257], csEB[257];
  __shared__ float wsA[4], wsB[4];
  __shared__ float bsl[32], esl[32];
  __shared__ float redU[16][64], redV[16][64];
  const int t = threadIdx.x;
  const int b = blockIdx.x;
  const int wv = t >> 6, lane = t & 63;
  const float4 a0 = ((const float4*)se1 )[t*2];
  const float4 a1v = ((const float4*)se1 )[t*2+1];
  const float4 b0 = ((const float4*)se1s)[t*2];
  const float4 b1v = ((const float4*)se1s)[t*2+1];
  ((float4*)s1l)[t*2]   = ((const float4*)s1g)[t*2];
  ((float4*)s1l)[t*2+1] = ((const float4*)s1g)[t*2+1];
  float sa = ((a0.x+a0.y)+(a0.z+a0.w)) + ((a1v.x+a1v.y)+(a1v.z+a1v.w));
  float sb = ((b0.x+b0.y)+(b0.z+b0.w)) + ((b1v.x+b1v.y)+(b1v.z+b1v.w));
  sa += __shfl_xor(sa, 1, 64); sb += __shfl_xor(sb, 1, 64);
  sa += __shfl_xor(sa, 2, 64); sb += __shfl_xor(sb, 2, 64);
  if ((t & 3) == 0) { csA[t>>2] = sa; csB[t>>2] = sb; }   // chunk(32) sums
  __syncthreads();
  // 4-wave shfl scan of 256 chunk sums
  if (t < 256) {
    float a = csA[t], bv = csB[t];
#pragma unroll
    for (int d = 1; d < 64; d <<= 1) {
      const float ua = __shfl_up(a, d, 64);
      const float ub = __shfl_up(bv, d, 64);
      if (lane >= d) { a += ua; bv += ub; }
    }
    csA[t] = a; csB[t] = bv;   // inclusive within 64-chunk group
    if (lane == 63) { wsA[wv] = a; wsB[wv] = bv; }
  }
  __syncthreads();
  if (t < 256) {
    float baseA = 0.f, baseB = 0.f;
    for (int q = 0; q < wv; ++q) { baseA += wsA[q]; baseB += wsB[q]; }
    csEA[t+1] = csA[t] + baseA;
    csEB[t+1] = csB[t] + baseB;
    if (t == 0) { csEA[0] = 0.f; csEB[0] = 0.f; }
  }
  __syncthreads();
  const int half = lane >> 5, m = lane & 31;
  // --- D part ---
  {
    const int kk = b*32 + 2*wv + half;
    const float tgt = -f2s[kk];
    int pos = 0;
#pragma unroll
    for (int s = NN; s; s >>= 1) {
      const int c = pos + s;
      if (c <= NN && s1l[c-1] < tgt) pos = c;
    }
    const int base = pos & ~31, cn = pos & 31;
    float ta = 0.f, tb = 0.f;
    if (m < cn) { ta = se1[base+m]; tb = se1s[base+m]; }
#pragma unroll
    for (int d = 1; d < 32; d <<= 1) {
      ta += __shfl_xor(ta, d, 64);
      tb += __shfl_xor(tb, d, 64);
    }
    if (m == 0) {
      const float PreA = csEA[pos>>5] + ta;
      const float PreB = csEB[pos>>5] + tb;
      const float T1 = csEA[256];
      const float e2 = eF2srt[kk], e2s = eF2ssrt[kk];
      const float D = fmaf(T1 - PreA, e2, PreB * e2s);
      const float bsv = e2 / D, esv = e2s / D;
      Bs[kk] = bsv; Es[kk] = esv;
      bsl[2*wv + half] = bsv; esl[2*wv + half] = esv;
    }
  }
  __syncthreads();
  // --- TU/TV: chunk b column totals from LDS factors ---
  {
    const int kk0 = b*32 + 2*wv, kk1 = kk0 + 1;
    const float s0v = seq[(size_t)inv[kk0]*OO + lane];
    const float s1v = seq[(size_t)inv[kk1]*OO + lane];
    redU[wv][lane] = bsl[2*wv]*s0v + bsl[2*wv+1]*s1v;
    redV[wv][lane] = esl[2*wv]*s0v + esl[2*wv+1]*s1v;
  }
  __syncthreads();
  if (wv == 0) {
    float r = 0.f;
#pragma unroll
    for (int q = 0; q < 16; ++q) r += redU[q][lane];
    TU[b*64 + lane] = r;
  } else if (wv == 1) {
    float r = 0.f;
#pragma unroll
    for (int q = 0; q < 16; ++q) r += redV[q][lane];
    TV[b*64 + lane] = r;
  }
}

// ============ K4: PU/PV prefix rows — parallel row-stage into LDS + fast LDS scan ============
// grid 256 x 1024
__global__ __launch_bounds__(1024) void k_apply(
    const float* __restrict__ seq, const int* __restrict__ inv,
    const float* __restrict__ Bs, const float* __restrict__ Es,
    const float* __restrict__ TU, const float* __restrict__ TV,
    float* __restrict__ PU, float* __restrict__ PV)
{
  __shared__ float puc[32][64], pvc[32][64];   // 16 KB: scaled rows
  __shared__ float rU[16][64], rV[16][64];     // 8 KB: base partials
  const int b = blockIdx.x, t = threadIdx.x;
  const int wv = t >> 6, lane = t & 63;
  // stage scaled rows (16 waves x 2 rows, parallel gathers)
#pragma unroll
  for (int s = 2*wv; s < 2*wv + 2; ++s) {
    const int kk = b*32 + s;
    const float sv = seq[(size_t)inv[kk]*OO + lane];
    puc[s][lane] = Bs[kk]*sv;
    pvc[s][lane] = Es[kk]*sv;
  }
  // base prefix over chunks < b, split across 16 waves
  float pu = 0.f, pv = 0.f;
  for (int c = wv; c < b; c += 16) {
    pu += TU[c*64 + lane];
    pv += TV[c*64 + lane];
  }
  rU[wv][lane] = pu; rV[wv][lane] = pv;
  __syncthreads();
  if (wv < 2) {
    const bool isV = (wv == 1);
    float r = 0.f;
#pragma unroll
    for (int q = 0; q < 16; ++q) r += (isV ? rV : rU)[q][lane];
    const float (*pc)[64] = isV ? pvc : puc;
    float* __restrict__ dst = isV ? PV : PU;
#pragma unroll 4
    for (int k = 0; k < 32; ++k) {
      dst[(size_t)(b*32 + k)*OO + lane] = r;
      r += pc[k][lane];
    }
    if (b == 255) dst[(size_t)NN*OO + lane] = r;   // grand total row
  }
}

// ============ K5: final combine + ELU (search in LDS-staged f2s) ============ grid 256 x 1024
__global__ __launch_bounds__(1024) void k_final(
    const float* __restrict__ f1, const float* __restrict__ E1,
    const float* __restrict__ E1s, const float* __restrict__ f2s,
    const float* __restrict__ PU, const float* __restrict__ PV,
    float* __restrict__ out)
{
  __shared__ float f2sl[NN];
  const int t = threadIdx.x;
  ((float4*)f2sl)[t*2]   = ((const float4*)f2s)[t*2];
  ((float4*)f2sl)[t*2+1] = ((const float4*)f2s)[t*2+1];
  __syncthreads();
  const int wv = t >> 6, lane = t & 63;
  const float utot = PU[(size_t)NN*OO + lane];
#pragma unroll
  for (int rr = 0; rr < 2; ++rr) {
    const int i = blockIdx.x*32 + 2*wv + rr;
    const float tgt = -f1[i];
    int pos = 0;
#pragma unroll
    for (int s = NN; s; s >>= 1) {
      const int c = pos + s;
      if (c <= NN && f2sl[c-1] < tgt) pos = c;
    }
    const float pu = PU[(size_t)pos*OO + lane];
    const float pv = PV[(size_t)pos*OO + lane];
    const float ret = E1[i]*(utot - pu) + E1s[i]*pv;
    out[(size_t)i*OO + lane] = (ret > 0.f) ? ret : expm1f(ret);
  }
}

extern "C" void kernel_launch(void* const* d_in, const int* in_sizes, int n_in,
                              void* d_out, int out_size, void* d_ws, size_t ws_size,
                              hipStream_t stream)
{
  (void)in_sizes; (void)n_in; (void)out_size; (void)ws_size;
  const float* x   = (const float*)d_in[0];
  const float* W1  = (const float*)d_in[1];
  const float* b1  = (const float*)d_in[2];
  const float* a1  = (const float*)d_in[3];
  const float* ba1 = (const float*)d_in[4];
  const float* a2  = (const float*)d_in[5];
  const float* ba2 = (const float*)d_in[6];
  float* out = (float*)d_out;

  float* w = (float*)d_ws;
  size_t off = 0;
  auto alloc = [&](size_t n) { float* p = w + off; off += (n + 63) & ~(size_t)63; return p; };
  float* seq  = alloc((size_t)NN*OO);
  float* f1   = alloc(NN);
  float* f2   = alloc(NN);
  float* E1   = alloc(NN);
  float* E1s  = alloc(NN);
  float* eF2  = alloc(NN);
  float* eF2s = alloc(NN);
  unsigned long long* keys = (unsigned long long*)alloc((size_t)4*NN);
  int*   inv  = (int*)alloc(NN);
  float* s1   = alloc(NN);
  float* se1  = alloc(NN);
  float* se1s = alloc(NN);
  float* f2s  = alloc(NN);
  float* eF2srt  = alloc(NN);
  float* eF2ssrt = alloc(NN);
  float* Bs   = alloc(NN);
  float* Es   = alloc(NN);
  float* TU   = alloc(256*64);
  float* TV   = alloc(256*64);
  float* PU   = alloc((size_t)(NN+1)*OO);
  float* PV   = alloc((size_t)(NN+1)*OO);

  k_gemm<<<512, 256, 0, stream>>>(x, W1, b1, a1, ba1, a2, ba2,
                                  seq, f1, f2, E1, E1s, eF2, eF2s, keys);
  k_rank<<<256, 512, 0, stream>>>(keys, f1, E1, E1s, f2, eF2, eF2s,
                                  s1, se1, se1s, f2s, eF2srt, eF2ssrt, inv);
  k_DT<<<256, 1024, 0, stream>>>(se1, se1s, s1, f2s, eF2srt, eF2ssrt,
                                 inv, seq, Bs, Es, TU, TV);
  k_apply<<<256, 1024, 0, stream>>>(seq, inv, Bs, Es, TU, TV, PU, PV);
  k_final<<<256, 1024, 0, stream>>>(f1, E1, E1s, f2s, PU, PV, out);
}

// Round 13
// 53.831 us; speedup vs baseline: 1.5044x; 1.0299x over previous
//
#include <hip/hip_runtime.h>
#include <math.h>

#define NN 8192
#define CC 256
#define OO 64
#define JW 8      // j's per wave in k_rank

// ============ K1: GEMM (W1 + x staged in LDS) + f1/f2 + exp tables + sortable keys ============
__global__ __launch_bounds__(256) void k_gemm(
    const float* __restrict__ x, const float* __restrict__ W1,
    const float* __restrict__ b1, const float* __restrict__ a1,
    const float* __restrict__ ba1, const float* __restrict__ a2,
    const float* __restrict__ ba2,
    float* __restrict__ seq,
    float* __restrict__ f1, float* __restrict__ f2,
    float* __restrict__ E1, float* __restrict__ E1s,
    float* __restrict__ eF2, float* __restrict__ eF2s,
    unsigned long long* __restrict__ keys /* [2][NN] */)
{
  __shared__ float w_lds[64][66];
  __shared__ float x_lds[16][256];
  const int t = threadIdx.x;
  const int p = t & 31;             // col pair: o = 2p, 2p+1
  const int g = t >> 5;             // 0..7 row group
  const int r0 = blockIdx.x*16 + g*2;
  const int r1 = r0 + 1;
  // stage 16 x-rows (coalesced)
  {
    const float4* xg = (const float4*)(x + (size_t)blockIdx.x*16*CC);
#pragma unroll
    for (int q = t; q < 1024; q += 256)
      ((float4*)x_lds)[q] = xg[q];
  }
  float c00 = 0.f, c01 = 0.f, c10 = 0.f, c11 = 0.f;
  for (int ct = 0; ct < 4; ++ct) {
    __syncthreads();
    for (int idx = t; idx < 4096; idx += 256) {
      const int o = idx >> 6, cc = idx & 63;
      w_lds[cc][o] = W1[o*CC + ct*64 + cc];
    }
    __syncthreads();
    const float* xr0 = &x_lds[g*2][ct*64];
    const float* xr1 = &x_lds[g*2+1][ct*64];
#pragma unroll 4
    for (int c = 0; c < 64; c += 4) {
      const float4 xa = *(const float4*)(xr0 + c);
      const float4 xb = *(const float4*)(xr1 + c);
      const float2 w0 = *(const float2*)&w_lds[c+0][2*p];
      const float2 w1 = *(const float2*)&w_lds[c+1][2*p];
      const float2 w2 = *(const float2*)&w_lds[c+2][2*p];
      const float2 w3 = *(const float2*)&w_lds[c+3][2*p];
      c00 = fmaf(xa.x, w0.x, c00); c00 = fmaf(xa.y, w1.x, c00);
      c00 = fmaf(xa.z, w2.x, c00); c00 = fmaf(xa.w, w3.x, c00);
      c01 = fmaf(xa.x, w0.y, c01); c01 = fmaf(xa.y, w1.y, c01);
      c01 = fmaf(xa.z, w2.y, c01); c01 = fmaf(xa.w, w3.y, c01);
      c10 = fmaf(xb.x, w0.x, c10); c10 = fmaf(xb.y, w1.x, c10);
      c10 = fmaf(xb.z, w2.x, c10); c10 = fmaf(xb.w, w3.x, c10);
      c11 = fmaf(xb.x, w0.y, c11); c11 = fmaf(xb.y, w1.y, c11);
      c11 = fmaf(xb.z, w2.y, c11); c11 = fmaf(xb.w, w3.y, c11);
    }
  }
  const float2 B2 = *(const float2*)&b1[2*p];
  const float v00 = c00 + B2.x, v01 = c01 + B2.y;
  const float v10 = c10 + B2.x, v11 = c11 + B2.y;
  *(float2*)&seq[(size_t)r0*OO + 2*p] = make_float2(v00, v01);
  *(float2*)&seq[(size_t)r1*OO + 2*p] = make_float2(v10, v11);
  const float2 A1 = *(const float2*)&a1[2*p];
  const float2 A2 = *(const float2*)&a2[2*p];
  float p1_0 = v00*A1.x + v01*A1.y;
  float p2_0 = v00*A2.x + v01*A2.y;
  float p1_1 = v10*A1.x + v11*A1.y;
  float p2_1 = v10*A2.x + v11*A2.y;
#pragma unroll
  for (int d = 1; d < 32; d <<= 1) {
    p1_0 += __shfl_xor(p1_0, d, 64);
    p2_0 += __shfl_xor(p2_0, d, 64);
    p1_1 += __shfl_xor(p1_1, d, 64);
    p2_1 += __shfl_xor(p2_1, d, 64);
  }
  if (p == 0) {
    const float bba1 = ba1[0], bba2 = ba2[0];
    const float t1a = p1_0 + bba1, t2a = p2_0 + bba2;
    const float t1b = p1_1 + bba1, t2b = p2_1 + bba2;
    f1[r0] = t1a; E1[r0] = expf(t1a); E1s[r0] = expf(0.01f*t1a);
    f2[r0] = t2a; eF2[r0] = expf(t2a); eF2s[r0] = expf(0.01f*t2a);
    f1[r1] = t1b; E1[r1] = expf(t1b); E1s[r1] = expf(0.01f*t1b);
    f2[r1] = t2b; eF2[r1] = expf(t2b); eF2s[r1] = expf(0.01f*t2b);
    unsigned u;
    u = __float_as_uint(t1a); u = (u & 0x80000000u) ? ~u : (u | 0x80000000u);
    keys[r0] = ((unsigned long long)u << 32) | (unsigned)r0;
    u = __float_as_uint(t1b); u = (u & 0x80000000u) ? ~u : (u | 0x80000000u);
    keys[r1] = ((unsigned long long)u << 32) | (unsigned)r1;
    u = __float_as_uint(t2a); u = (u & 0x80000000u) ? ~u : (u | 0x80000000u);
    keys[NN + r0] = ((unsigned long long)u << 32) | (unsigned)r0;
    u = __float_as_uint(t2b); u = (u & 0x80000000u) ? ~u : (u | 0x80000000u);
    keys[NN + r1] = ((unsigned long long)u << 32) | (unsigned)r1;
  }
}

// ============ K2: rank counting from LDS-staged keys + sorted scatters (+inv1) ============
__global__ __launch_bounds__(512) void k_rank(
    const unsigned long long* __restrict__ keys,
    const float* __restrict__ f1, const float* __restrict__ E1,
    const float* __restrict__ E1s, const float* __restrict__ f2,
    const float* __restrict__ eF2, const float* __restrict__ eF2s,
    float* __restrict__ s1, float* __restrict__ se1, float* __restrict__ se1s,
    int* __restrict__ inv1,
    float* __restrict__ f2s, float* __restrict__ eF2srt,
    float* __restrict__ eF2ssrt, int* __restrict__ inv)
{
  __shared__ unsigned long long skl[NN];   // 64 KB
  const int t = threadIdx.x;
  const int lane = t & 63, wv = t >> 6;    // 8 waves
  const int gw = blockIdx.x*8 + wv;        // 0..2047
  const int bj = gw*JW;
  const int arr = bj >> 13;                // uniform per block (64-j aligned)
  const int jb = bj & (NN-1);
  const unsigned long long* kb = keys + ((size_t)arr << 13);
  for (int q = t; q < NN/2; q += 512)
    ((ulonglong2*)skl)[q] = ((const ulonglong2*)kb)[q];
  __syncthreads();
  unsigned long long K[JW];
#pragma unroll
  for (int q = 0; q < JW; ++q) {
    const unsigned long long kk = skl[jb + q];
    const unsigned lo = __builtin_amdgcn_readfirstlane((unsigned)kk);
    const unsigned hi = __builtin_amdgcn_readfirstlane((unsigned)(kk >> 32));
    K[q] = ((unsigned long long)hi << 32) | lo;
  }
  int cnt[JW];
#pragma unroll
  for (int q = 0; q < JW; ++q) cnt[q] = 0;
#pragma unroll 4
  for (int c = 0; c < NN/64; ++c) {
    const unsigned long long sk = skl[c*64 + lane];
#pragma unroll
    for (int q = 0; q < JW; ++q)
      cnt[q] += (sk < K[q]) ? 1 : 0;
  }
#pragma unroll
  for (int q = 0; q < JW; ++q) {
    int r = cnt[q];
#pragma unroll
    for (int d = 1; d < 64; d <<= 1) r += __shfl_xor(r, d, 64);
    if (lane == 0) {
      const int i = jb + q;
      if (arr == 0) {
        s1[r] = f1[i]; se1[r] = E1[i]; se1s[r] = E1s[i]; inv1[r] = i;
      } else {
        inv[r] = i; f2s[r] = f2[i]; eF2srt[r] = eF2[i]; eF2ssrt[r] = eF2s[i];
      }
    }
  }
}

// ============ K3: D-factors + kpos (LDS bsearch) + TU/TV chunk totals ============
__global__ __launch_bounds__(1024) void k_DT(
    const float* __restrict__ se1, const float* __restrict__ se1s,
    const float* __restrict__ s1g,
    const float* __restrict__ f2s, const float* __restrict__ eF2srt,
    const float* __restrict__ eF2ssrt, const int* __restrict__ inv,
    const float* __restrict__ seq,
    float* __restrict__ Bs, float* __restrict__ Es,
    int* __restrict__ kpos, float* __restrict__ TU, float* __restrict__ TV)
{
  __shared__ float s1l[NN];          // 32 KB (sorted f1)
  __shared__ float f2sl[NN];         // 32 KB (sorted f2)
  __shared__ float csA[256], csB[256];
  __shared__ float csEA[257], csEB[257];
  __shared__ float wsA[4], wsB[4];
  __shared__ float bsl[32], esl[32];
  __shared__ float redU[16][64], redV[16][64];
  const int t = threadIdx.x;
  const int b = blockIdx.x;
  const int wv = t >> 6, lane = t & 63;
  const float4 a0 = ((const float4*)se1 )[t*2];
  const float4 a1v = ((const float4*)se1 )[t*2+1];
  const float4 b0 = ((const float4*)se1s)[t*2];
  const float4 b1v = ((const float4*)se1s)[t*2+1];
  ((float4*)s1l)[t*2]   = ((const float4*)s1g)[t*2];
  ((float4*)s1l)[t*2+1] = ((const float4*)s1g)[t*2+1];
  ((float4*)f2sl)[t*2]   = ((const float4*)f2s)[t*2];
  ((float4*)f2sl)[t*2+1] = ((const float4*)f2s)[t*2+1];
  float sa = ((a0.x+a0.y)+(a0.z+a0.w)) + ((a1v.x+a1v.y)+(a1v.z+a1v.w));
  float sb = ((b0.x+b0.y)+(b0.z+b0.w)) + ((b1v.x+b1v.y)+(b1v.z+b1v.w));
  sa += __shfl_xor(sa, 1, 64); sb += __shfl_xor(sb, 1, 64);
  sa += __shfl_xor(sa, 2, 64); sb += __shfl_xor(sb, 2, 64);
  if ((t & 3) == 0) { csA[t>>2] = sa; csB[t>>2] = sb; }   // chunk(32) sums
  __syncthreads();
  // 4-wave shfl scan of 256 chunk sums
  if (t < 256) {
    float a = csA[t], bv = csB[t];
#pragma unroll
    for (int d = 1; d < 64; d <<= 1) {
      const float ua = __shfl_up(a, d, 64);
      const float ub = __shfl_up(bv, d, 64);
      if (lane >= d) { a += ua; bv += ub; }
    }
    csA[t] = a; csB[t] = bv;
    if (lane == 63) { wsA[wv] = a; wsB[wv] = bv; }
  }
  __syncthreads();
  if (t < 256) {
    float baseA = 0.f, baseB = 0.f;
    for (int q = 0; q < wv; ++q) { baseA += wsA[q]; baseB += wsB[q]; }
    csEA[t+1] = csA[t] + baseA;
    csEB[t+1] = csB[t] + baseB;
    if (t == 0) { csEA[0] = 0.f; csEB[0] = 0.f; }
  }
  __syncthreads();
  const int half = lane >> 5, m = lane & 31;
  // --- D part ---
  {
    const int kk = b*32 + 2*wv + half;
    const float tgt = -f2sl[kk];
    int pos = 0;
#pragma unroll
    for (int s = NN; s; s >>= 1) {
      const int c = pos + s;
      if (c <= NN && s1l[c-1] < tgt) pos = c;
    }
    const int base = pos & ~31, cn = pos & 31;
    float ta = 0.f, tb = 0.f;
    if (m < cn) { ta = se1[base+m]; tb = se1s[base+m]; }
#pragma unroll
    for (int d = 1; d < 32; d <<= 1) {
      ta += __shfl_xor(ta, d, 64);
      tb += __shfl_xor(tb, d, 64);
    }
    if (m == 0) {
      const float PreA = csEA[pos>>5] + ta;
      const float PreB = csEB[pos>>5] + tb;
      const float T1 = csEA[256];
      const float e2 = eF2srt[kk], e2s = eF2ssrt[kk];
      const float D = fmaf(T1 - PreA, e2, PreB * e2s);
      const float bsv = e2 / D, esv = e2s / D;
      Bs[kk] = bsv; Es[kk] = esv;
      bsl[2*wv + half] = bsv; esl[2*wv + half] = esv;
    }
  }
  // --- kpos: kpos[r] = #{ f2 < -s1[r] } via binary search in LDS sorted f2 ---
  if (t < 32) {
    const int r = b*32 + t;
    const float tgt = -s1l[r];
    int pos = 0;
#pragma unroll
    for (int s = NN; s; s >>= 1) {
      const int c = pos + s;
      if (c <= NN && f2sl[c-1] < tgt) pos = c;
    }
    kpos[r] = pos;
  }
  __syncthreads();
  // --- TU/TV: chunk b column totals from LDS factors ---
  {
    const int kk0 = b*32 + 2*wv, kk1 = kk0 + 1;
    const float s0v = seq[(size_t)inv[kk0]*OO + lane];
    const float s1v = seq[(size_t)inv[kk1]*OO + lane];
    redU[wv][lane] = bsl[2*wv]*s0v + bsl[2*wv+1]*s1v;
    redV[wv][lane] = esl[2*wv]*s0v + esl[2*wv+1]*s1v;
  }
  __syncthreads();
  if (wv == 0) {
    float r = 0.f;
#pragma unroll
    for (int q = 0; q < 16; ++q) r += redU[q][lane];
    TU[b*64 + lane] = r;
  } else if (wv == 1) {
    float r = 0.f;
#pragma unroll
    for (int q = 0; q < 16; ++q) r += redV[q][lane];
    TV[b*64 + lane] = r;
  }
}

// ============ K4: merged prefix + output (no PU/PV tables), 1024 threads ============
// block b: rows kk in [32b,32b+32); emits all f1-sorted rows r with kpos in [32b,32b+32) (+1 top for b=255)
__global__ __launch_bounds__(1024) void k_merge(
    const int* __restrict__ kpos, const int* __restrict__ inv,
    const int* __restrict__ inv1,
    const float* __restrict__ se1, const float* __restrict__ se1s,
    const float* __restrict__ Bs, const float* __restrict__ Es,
    const float* __restrict__ seq,
    const float* __restrict__ TU, const float* __restrict__ TV,
    float* __restrict__ out)
{
  __shared__ int kposl[NN];                    // 32 KB
  __shared__ float pu[33][64], pv[33][64];     // 16.5 KB
  __shared__ float rA[16][64], rB[16][64], rC[16][64];
  __shared__ int bnd[2];
  const int t = threadIdx.x, lane = t & 63, wv = t >> 6, b = blockIdx.x;
  for (int q = t; q < NN/4; q += 1024)
    ((int4*)kposl)[q] = ((const int4*)kpos)[q];
  // base (chunks < b) and grand total of TU; base of TV — split over 16 waves
  float pbu = 0.f, pbv = 0.f, ptu = 0.f;
  for (int c = wv; c < 256; c += 16) {
    const float tu = TU[c*64 + lane], tv = TV[c*64 + lane];
    ptu += tu;
    if (c < b) { pbu += tu; pbv += tv; }
  }
  rA[wv][lane] = pbu; rB[wv][lane] = pbv; rC[wv][lane] = ptu;
  // stage scaled rows (16 waves x 2 rows, parallel gathers)
  {
    const int kk0 = b*32 + 2*wv, kk1 = kk0 + 1;
    const float sv0 = seq[(size_t)inv[kk0]*OO + lane];
    const float sv1 = seq[(size_t)inv[kk1]*OO + lane];
    pu[2*wv+1][lane] = Bs[kk0]*sv0; pv[2*wv+1][lane] = Es[kk0]*sv0;
    pu[2*wv+2][lane] = Bs[kk1]*sv1; pv[2*wv+2][lane] = Es[kk1]*sv1;
  }
  if (wv == 0) { pu[0][lane] = 0.f; pv[0][lane] = 0.f; }
  __syncthreads();
  if (t == 0) {   // emit range boundaries in descending kposl
    const int hi = 32*b + 32 + (b == 255 ? 1 : 0);
    int pos = 0;
    for (int s = NN; s; s >>= 1) { const int c = pos+s; if (c <= NN && kposl[c-1] >= hi) pos = c; }
    bnd[0] = pos;
    pos = 0;
    const int lo = 32*b;
    for (int s = NN; s; s >>= 1) { const int c = pos+s; if (c <= NN && kposl[c-1] >= lo) pos = c; }
    bnd[1] = pos;
  }
  float base_u = 0.f, base_v = 0.f, utot = 0.f;
#pragma unroll
  for (int q = 0; q < 16; ++q) {
    base_u += rA[q][lane]; base_v += rB[q][lane]; utot += rC[q][lane];
  }
  // Hillis-Steele over rows 1..32 (2 rows per thread-slice): pu[m] = sum rows 1..m
  for (int d = 1; d < 32; d <<= 1) {
    const int rowA = wv + 1;        // rows 1..16
    const int rowB = wv + 17;       // rows 17..32
    const int srcA = rowA - d, srcB = rowB - d;
    const float aA = (srcA >= 0) ? pu[srcA][lane] : 0.f;
    const float vA = (srcA >= 0) ? pv[srcA][lane] : 0.f;
    const float aB = (srcB >= 0) ? pu[srcB][lane] : 0.f;
    const float vB = (srcB >= 0) ? pv[srcB][lane] : 0.f;
    __syncthreads();
    pu[rowA][lane] += aA; pv[rowA][lane] += vA;
    pu[rowB][lane] += aB; pv[rowB][lane] += vB;
    __syncthreads();
  }
  // parallel emits
  const int r0 = bnd[0], r1 = bnd[1];
  for (int r = r0 + wv; r < r1; r += 16) {
    const int kl = kposl[r] - 32*b;
    const float ret = se1[r]*(utot - (base_u + pu[kl][lane]))
                    + se1s[r]*(base_v + pv[kl][lane]);
    out[(size_t)inv1[r]*OO + lane] = (ret > 0.f) ? ret : expm1f(ret);
  }
}

extern "C" void kernel_launch(void* const* d_in, const int* in_sizes, int n_in,
                              void* d_out, int out_size, void* d_ws, size_t ws_size,
                              hipStream_t stream)
{
  (void)in_sizes; (void)n_in; (void)out_size; (void)ws_size;
  const float* x   = (const float*)d_in[0];
  const float* W1  = (const float*)d_in[1];
  const float* b1  = (const float*)d_in[2];
  const float* a1  = (const float*)d_in[3];
  const float* ba1 = (const float*)d_in[4];
  const float* a2  = (const float*)d_in[5];
  const float* ba2 = (const float*)d_in[6];
  float* out = (float*)d_out;

  float* w = (float*)d_ws;
  size_t off = 0;
  auto alloc = [&](size_t n) { float* p = w + off; off += (n + 63) & ~(size_t)63; return p; };
  float* seq  = alloc((size_t)NN*OO);
  float* f1   = alloc(NN);
  float* f2   = alloc(NN);
  float* E1   = alloc(NN);
  float* E1s  = alloc(NN);
  float* eF2  = alloc(NN);
  float* eF2s = alloc(NN);
  unsigned long long* keys = (unsigned long long*)alloc((size_t)4*NN);
  int*   inv1 = (int*)alloc(NN);
  int*   inv  = (int*)alloc(NN);
  float* s1   = alloc(NN);
  float* se1  = alloc(NN);
  float* se1s = alloc(NN);
  float* f2s  = alloc(NN);
  float* eF2srt  = alloc(NN);
  float* eF2ssrt = alloc(NN);
  float* Bs   = alloc(NN);
  float* Es   = alloc(NN);
  int*   kpos = (int*)alloc(NN);
  float* TU   = alloc(256*64);
  float* TV   = alloc(256*64);

  k_gemm<<<512, 256, 0, stream>>>(x, W1, b1, a1, ba1, a2, ba2,
                                  seq, f1, f2, E1, E1s, eF2, eF2s, keys);
  k_rank<<<256, 512, 0, stream>>>(keys, f1, E1, E1s, f2, eF2, eF2s,
                                  s1, se1, se1s, inv1, f2s, eF2srt, eF2ssrt, inv);
  k_DT<<<256, 1024, 0, stream>>>(se1, se1s, s1, f2s, eF2srt, eF2ssrt,
                                 inv, seq, Bs, Es, kpos, TU, TV);
  k_merge<<<256, 1024, 0, stream>>>(kpos, inv, inv1, se1, se1s, Bs, Es,
                                    seq, TU, TV, out);
}